// Round 13
// baseline (293.495 us; speedup 1.0000x reference)
//
#include <hip/hip_runtime.h>
#include <cstddef>
#include <cstdint>

#define SCAN_B 512

using bf16x8 = __attribute__((ext_vector_type(8))) short;
using f32x4  = __attribute__((ext_vector_type(4))) float;

__device__ __forceinline__ unsigned short f2bf(float f) {
    unsigned int u = __builtin_bit_cast(unsigned int, f);
    return (unsigned short)((u + 0x7FFFu + ((u >> 16) & 1u)) >> 16);  // RNE
}
__device__ __forceinline__ float bf2f(unsigned short b) {
    unsigned int u = ((unsigned int)b) << 16;
    return __builtin_bit_cast(float, u);
}
__device__ __forceinline__ float i2f(int i) { return __builtin_bit_cast(float, i); }
__device__ __forceinline__ float u2f(unsigned int u) { return __builtin_bit_cast(float, u); }
__device__ __forceinline__ void gload_lds16(const void* g, void* l) {
    __builtin_amdgcn_global_load_lds((const __attribute__((address_space(1))) void*)g,
                                     (__attribute__((address_space(3))) void*)l, 16, 0, 0);
}

// ---------------- CSR hist (+rank) fused with f32->bf16 conversions ----------------
__global__ void hist_conv_k(const int* __restrict__ dst, int* __restrict__ counts,
                            int* __restrict__ rank, int E, int histBlocks,
                            const float* __restrict__ x, const float* __restrict__ Wr0,
                            const float* __restrict__ Wt0, const float* __restrict__ Wr1,
                            const float* __restrict__ Wt1, const float* __restrict__ Wr2,
                            const float* __restrict__ Wt2, unsigned short* __restrict__ x_bf,
                            unsigned short* __restrict__ Wr0b, unsigned short* __restrict__ Wt0b,
                            unsigned short* __restrict__ Wr1b, unsigned short* __restrict__ Wt1b,
                            unsigned short* __restrict__ Wr2b, unsigned short* __restrict__ Wt2b,
                            int n4x) {
    if ((int)blockIdx.x < histBlocks) {
        int e = blockIdx.x * 256 + threadIdx.x;
        if (e < E) rank[e] = atomicAdd(&counts[dst[e]], 1);
        return;
    }
    int j = (blockIdx.x - histBlocks) * 256 + threadIdx.x;
    const float* s;
    unsigned short* d;
    if (j < n4x) { s = x; d = x_bf; }
    else {
        j -= n4x;
        if (j < 8192) { s = Wr0; d = Wr0b; }
        else { j -= 8192;
        if (j < 8192) { s = Wt0; d = Wt0b; }
        else { j -= 8192;
        if (j < 16384) { s = Wr1; d = Wr1b; }
        else { j -= 16384;
        if (j < 16384) { s = Wt1; d = Wt1b; }
        else { j -= 16384;
        if (j < 4096) { s = Wr2; d = Wr2b; }
        else { j -= 4096;
        if (j >= 4096) return;
        s = Wt2; d = Wt2b; } } } } }
    }
    float4 v = reinterpret_cast<const float4*>(s)[j];
    ushort4 o;
    o.x = f2bf(v.x); o.y = f2bf(v.y); o.z = f2bf(v.z); o.w = f2bf(v.w);
    reinterpret_cast<ushort4*>(d)[j] = o;
}

__global__ void scan1_k(const int* __restrict__ counts, int* __restrict__ partial,
                        int* __restrict__ blocksum, int Nn) {
    __shared__ int sh[SCAN_B];
    int i = blockIdx.x * SCAN_B + threadIdx.x;
    int v = (i < Nn) ? counts[i] : 0;
    sh[threadIdx.x] = v;
    __syncthreads();
    for (int off = 1; off < SCAN_B; off <<= 1) {
        int t = (threadIdx.x >= (unsigned)off) ? sh[threadIdx.x - off] : 0;
        __syncthreads();
        sh[threadIdx.x] += t;
        __syncthreads();
    }
    if (i < Nn) partial[i] = sh[threadIdx.x];
    if (threadIdx.x == SCAN_B - 1) blocksum[blockIdx.x] = sh[threadIdx.x];
}

// scan3 with inlined block-prefix: wave 0 reduces blocksum[0..bx)
__global__ void scan3b_k(const int* __restrict__ partial, const int* __restrict__ blocksum,
                         int* __restrict__ offsets, int Nn) {
    __shared__ int add_s;
    int bx = blockIdx.x;
    if (threadIdx.x < 64) {
        int s = 0;
        for (int j = threadIdx.x; j < bx; j += 64) s += blocksum[j];
        #pragma unroll
        for (int off = 32; off > 0; off >>= 1) s += __shfl_down(s, off, 64);
        if (threadIdx.x == 0) add_s = s;
    }
    __syncthreads();
    int i = bx * SCAN_B + threadIdx.x;
    if (i >= Nn) return;
    offsets[i + 1] = partial[i] + add_s;
    if (i == 0) offsets[0] = 0;
}

// atomic-free scatter: pos fully determined by offsets + precomputed rank
__global__ void fill2_k(const int* __restrict__ src, const int* __restrict__ dst,
                        const float* __restrict__ ew, const int* __restrict__ offsets,
                        const int* __restrict__ rank, int2* __restrict__ e_sw, int E) {
    int e = blockIdx.x * blockDim.x + threadIdx.x;
    if (e >= E) return;
    int pos = offsets[dst[e]] + rank[e];
    e_sw[pos] = make_int2(src[e], __builtin_bit_cast(int, ew[e]));
}

// ---------------- gather F=128 (CSR, bf16, f32 acc, 8-deep ILP) ----------------
__global__ void gather128_k(const unsigned short* __restrict__ x, const int* __restrict__ offsets,
                            const int2* __restrict__ e_sw, unsigned short* __restrict__ agg, int Nn) {
    int wid = __builtin_amdgcn_readfirstlane((blockIdx.x * blockDim.x + threadIdx.x) >> 6);
    int lane = threadIdx.x & 63;
    if (wid >= Nn) return;
    int p = offsets[wid], end = offsets[wid + 1];
    const char* xb = (const char*)x;
    const unsigned loff = lane * 4u;
    float a0 = 0.f, a1 = 0.f;
    for (; p + 8 <= end; p += 8) {
        int2 ee[8];
        #pragma unroll
        for (int i = 0; i < 8; ++i) ee[i] = e_sw[p + i];
        unsigned vv[8];
        #pragma unroll
        for (int i = 0; i < 8; ++i)
            vv[i] = *reinterpret_cast<const unsigned*>(xb + ((unsigned)ee[i].x * 256u + loff));
        #pragma unroll
        for (int i = 0; i < 8; ++i) {
            float w = i2f(ee[i].y);
            a0 += w * u2f(vv[i] << 16); a1 += w * u2f(vv[i] & 0xFFFF0000u);
        }
    }
    for (; p < end; ++p) {
        int2 e0 = e_sw[p];
        unsigned v0 = *reinterpret_cast<const unsigned*>(xb + ((unsigned)e0.x * 256u + loff));
        float w = i2f(e0.y);
        a0 += w * u2f(v0 << 16); a1 += w * u2f(v0 & 0xFFFF0000u);
    }
    unsigned o = (unsigned)f2bf(a0) | ((unsigned)f2bf(a1) << 16);
    *reinterpret_cast<unsigned*>(agg + (size_t)wid * 128 + lane * 2) = o;
}

// ---------------- fused: gather F=256 with inline BN+ReLU  ∥  bn_relu pass ----------------
// Roles INTERLEAVED across blockIdx (bx%7==6 -> bn-relu) so the streaming
// bn pass runs inside the gather's latency shadow instead of trailing it.
// Both roles only READ h_raw; outputs (agg vs hN) are disjoint -> no hazard.
__global__ void gather_bn_k(const unsigned short* __restrict__ h_raw,
                            const float* __restrict__ sums, const float* __restrict__ sumsq,
                            const float* __restrict__ g, const float* __restrict__ be,
                            const int* __restrict__ offsets, const int2* __restrict__ e_sw,
                            unsigned short* __restrict__ agg, unsigned short* __restrict__ hN,
                            float invN, int Nn) {
    const int lane = threadIdx.x & 63;
    const int bx = blockIdx.x;
    if (bx % 7 == 6) {
        // ---- bn_relu role (grid-stride over Nn*64 float4-chunks) ----
        int bidx = bx / 7;
        int nbn = (int)gridDim.x / 7;
        int total4 = Nn * 64;
        int stride = nbn * 256;
        for (int t = bidx * 256 + threadIdx.x; t < total4; t += stride) {
            int f0 = (t & 63) * 4;
            float4 sm = *reinterpret_cast<const float4*>(sums + f0);
            float4 sq = *reinterpret_cast<const float4*>(sumsq + f0);
            float4 gg = *reinterpret_cast<const float4*>(g + f0);
            float4 bb = *reinterpret_cast<const float4*>(be + f0);
            float smv[4] = {sm.x, sm.y, sm.z, sm.w};
            float sqv[4] = {sq.x, sq.y, sq.z, sq.w};
            float ggv[4] = {gg.x, gg.y, gg.z, gg.w};
            float bbv[4] = {bb.x, bb.y, bb.z, bb.w};
            ushort4 v = reinterpret_cast<const ushort4*>(h_raw)[t];
            unsigned short vv[4] = {v.x, v.y, v.z, v.w};
            ushort4 o;
            unsigned short* op = &o.x;
            #pragma unroll
            for (int c = 0; c < 4; ++c) {
                float mu = smv[c] * invN;
                float var = sqv[c] * invN - mu * mu;
                float sc = ggv[c] * rsqrtf(var + 1e-5f);
                float sh = bbv[c] - mu * sc;
                op[c] = f2bf(fmaxf(bf2f(vv[c]) * sc + sh, 0.f));
            }
            reinterpret_cast<ushort4*>(hN)[t] = o;
        }
        return;
    }
    // ---- gather role: one wave per node, 4 features per lane, inline BN ----
    int gidx = bx - (bx + 1) / 7;     // gather-block index (bn blocks removed)
    int wid = __builtin_amdgcn_readfirstlane((gidx * 256 + (int)threadIdx.x) >> 6);
    if (wid >= Nn) return;
    int f0 = lane * 4;
    float4 sm = *reinterpret_cast<const float4*>(sums + f0);
    float4 sq = *reinterpret_cast<const float4*>(sumsq + f0);
    float4 gg = *reinterpret_cast<const float4*>(g + f0);
    float4 bb = *reinterpret_cast<const float4*>(be + f0);
    float sc0, sc1, sc2, sc3, sh0, sh1, sh2, sh3;
    {
        float mu, var;
        mu = sm.x * invN; var = sq.x * invN - mu * mu; sc0 = gg.x * rsqrtf(var + 1e-5f); sh0 = bb.x - mu * sc0;
        mu = sm.y * invN; var = sq.y * invN - mu * mu; sc1 = gg.y * rsqrtf(var + 1e-5f); sh1 = bb.y - mu * sc1;
        mu = sm.z * invN; var = sq.z * invN - mu * mu; sc2 = gg.z * rsqrtf(var + 1e-5f); sh2 = bb.z - mu * sc2;
        mu = sm.w * invN; var = sq.w * invN - mu * mu; sc3 = gg.w * rsqrtf(var + 1e-5f); sh3 = bb.w - mu * sc3;
    }
    int p = offsets[wid], end = offsets[wid + 1];
    const char* xb = (const char*)h_raw;
    const unsigned loff = lane * 8u;
    float a0 = 0.f, a1 = 0.f, a2 = 0.f, a3 = 0.f;
    for (; p + 8 <= end; p += 8) {
        int2 ee[8];
        #pragma unroll
        for (int i = 0; i < 8; ++i) ee[i] = e_sw[p + i];
        uint2 vv[8];
        #pragma unroll
        for (int i = 0; i < 8; ++i)
            vv[i] = *reinterpret_cast<const uint2*>(xb + ((unsigned)ee[i].x * 512u + loff));
        #pragma unroll
        for (int i = 0; i < 8; ++i) {
            float w = i2f(ee[i].y);
            a0 += w * fmaxf(u2f(vv[i].x << 16) * sc0 + sh0, 0.f);
            a1 += w * fmaxf(u2f(vv[i].x & 0xFFFF0000u) * sc1 + sh1, 0.f);
            a2 += w * fmaxf(u2f(vv[i].y << 16) * sc2 + sh2, 0.f);
            a3 += w * fmaxf(u2f(vv[i].y & 0xFFFF0000u) * sc3 + sh3, 0.f);
        }
    }
    for (; p < end; ++p) {
        int2 e0 = e_sw[p];
        uint2 v0 = *reinterpret_cast<const uint2*>(xb + ((unsigned)e0.x * 512u + loff));
        float w = i2f(e0.y);
        a0 += w * fmaxf(u2f(v0.x << 16) * sc0 + sh0, 0.f);
        a1 += w * fmaxf(u2f(v0.x & 0xFFFF0000u) * sc1 + sh1, 0.f);
        a2 += w * fmaxf(u2f(v0.y << 16) * sc2 + sh2, 0.f);
        a3 += w * fmaxf(u2f(v0.y & 0xFFFF0000u) * sc3 + sh3, 0.f);
    }
    uint2 o;
    o.x = (unsigned)f2bf(a0) | ((unsigned)f2bf(a1) << 16);
    o.y = (unsigned)f2bf(a2) | ((unsigned)f2bf(a3) << 16);
    *reinterpret_cast<uint2*>(agg + (size_t)wid * 256 + lane * 4) = o;
}

// ---- final: out[node] = root[node] + sum_e w * t[src], F=64, 16 lanes/node ----
__global__ void gather_out_k(const unsigned short* __restrict__ t, const float* __restrict__ root,
                             const int* __restrict__ offsets, const int2* __restrict__ e_sw,
                             float* __restrict__ out, int Nn) {
    int gt = blockIdx.x * blockDim.x + threadIdx.x;
    int node = gt >> 4;
    int li = gt & 15;
    if (node >= Nn) return;
    int p = offsets[node], end = offsets[node + 1];
    const char* tb = (const char*)t;
    const unsigned loff = li * 8u;
    float a0 = 0.f, a1 = 0.f, a2 = 0.f, a3 = 0.f;
    for (; p + 8 <= end; p += 8) {
        int2 ee[8];
        #pragma unroll
        for (int i = 0; i < 8; ++i) ee[i] = e_sw[p + i];
        uint2 vv[8];
        #pragma unroll
        for (int i = 0; i < 8; ++i)
            vv[i] = *reinterpret_cast<const uint2*>(tb + ((unsigned)ee[i].x * 128u + loff));
        #pragma unroll
        for (int i = 0; i < 8; ++i) {
            float w = i2f(ee[i].y);
            a0 += w * u2f(vv[i].x << 16); a1 += w * u2f(vv[i].x & 0xFFFF0000u);
            a2 += w * u2f(vv[i].y << 16); a3 += w * u2f(vv[i].y & 0xFFFF0000u);
        }
    }
    for (; p < end; ++p) {
        int2 e0 = e_sw[p];
        uint2 v0 = *reinterpret_cast<const uint2*>(tb + ((unsigned)e0.x * 128u + loff));
        float w = i2f(e0.y);
        a0 += w * u2f(v0.x << 16); a1 += w * u2f(v0.x & 0xFFFF0000u);
        a2 += w * u2f(v0.y << 16); a3 += w * u2f(v0.y & 0xFFFF0000u);
    }
    float4 r = *reinterpret_cast<const float4*>(root + (size_t)node * 64 + li * 4);
    float4 o = make_float4(r.x + a0, r.y + a1, r.z + a2, r.w + a3);
    *reinterpret_cast<float4*>(out + (size_t)node * 64 + li * 4) = o;
}

// ---------------- bf16 MFMA GEMM: 8 waves, BK=32, dbuf stage-early, 4 blocks/CU ----
template<int K, int O, int MODE>
__global__ __launch_bounds__(512, 4) void gemm_mfma_k(
        const unsigned short* __restrict__ A, const unsigned short* __restrict__ Wa,
        const unsigned short* __restrict__ X, const unsigned short* __restrict__ Wb,
        const float* __restrict__ bias, unsigned short* __restrict__ out_bf,
        float* __restrict__ out_f, float* __restrict__ sums, float* __restrict__ sumsq,
        int Nn) {
    constexpr int BM = 128, BN = 128;
    constexpr int MI = 4;
    constexpr int OJ = 2;
    constexpr int KSTEPS = K / 32;
    constexpr int NT = (MODE == 0 ? 2 : 1) * KSTEPS;
    __shared__ unsigned short As[2][BM * 32];
    __shared__ unsigned short Bs[2][BN * 32];
    const int tid = threadIdx.x;
    const int w = tid >> 6, l = tid & 63;
    const int wr = w >> 2, wc = w & 3;
    const int lrow = l & 15, kgrp = l >> 4;
    int bx = blockIdx.x;
    bx = (bx & 7) * (gridDim.x >> 3) + (bx >> 3);   // bijective (gridDim.x % 8 == 0)
    const int m0 = bx * BM;
    const int n0 = blockIdx.y * BN;
    const int srow = tid >> 2, sslot = tid & 3;
    const int gslot = sslot ^ ((srow >> 1) & 3);

    auto stage = [&](int buf, int t) {
        int ph = t / KSTEPS;
        int k0 = (t % KSTEPS) * 32;
        const unsigned short* Ap = (MODE == 0 && ph) ? X : A;
        const unsigned short* Wp = (MODE == 0 && ph) ? Wb : Wa;
        gload_lds16(Ap + (size_t)(m0 + srow) * K + k0 + (gslot << 3), &As[buf][w * 512]);
        gload_lds16(Wp + (size_t)(n0 + srow) * K + k0 + (gslot << 3), &Bs[buf][w * 512]);
    };

    f32x4 acc[MI][OJ];
    #pragma unroll
    for (int i = 0; i < MI; ++i)
        #pragma unroll
        for (int j = 0; j < OJ; ++j) {
            f32x4 z = {0.f, 0.f, 0.f, 0.f};
            acc[i][j] = z;
        }

    stage(0, 0);
    __syncthreads();
    #pragma unroll
    for (int t = 0; t < NT; ++t) {
        const int cur = t & 1;
        if (t + 1 < NT) stage(cur ^ 1, t + 1);
        bf16x8 a[MI], b[OJ];
        #pragma unroll
        for (int mi = 0; mi < MI; ++mi) {
            int row = wr * 64 + mi * 16 + lrow;
            int slot = kgrp ^ ((row >> 1) & 3);
            a[mi] = *reinterpret_cast<const bf16x8*>(&As[cur][row * 32 + slot * 8]);
        }
        #pragma unroll
        for (int oj = 0; oj < OJ; ++oj) {
            int row = wc * 32 + oj * 16 + lrow;
            int slot = kgrp ^ ((row >> 1) & 3);
            b[oj] = *reinterpret_cast<const bf16x8*>(&Bs[cur][row * 32 + slot * 8]);
        }
        #pragma unroll
        for (int mi = 0; mi < MI; ++mi)
            #pragma unroll
            for (int oj = 0; oj < OJ; ++oj)
                acc[mi][oj] = __builtin_amdgcn_mfma_f32_16x16x32_bf16(
                    a[mi], b[oj], acc[mi][oj], 0, 0, 0);
        __syncthreads();
    }

    #pragma unroll
    for (int oj = 0; oj < OJ; ++oj) {
        int col = n0 + wc * 32 + oj * 16 + lrow;
        float bcol = bias[col];
        float s = 0.f, q = 0.f;
        #pragma unroll
        for (int mi = 0; mi < MI; ++mi) {
            #pragma unroll
            for (int r = 0; r < 4; ++r) {
                int row = m0 + wr * 64 + mi * 16 + kgrp * 4 + r;
                float v = acc[mi][oj][r] + bcol;
                if (row < Nn) {
                    out_bf[(size_t)row * O + col] = f2bf(v);
                    s += v; q += v * v;
                }
            }
        }
        s += __shfl_xor(s, 16, 64); q += __shfl_xor(q, 16, 64);
        s += __shfl_xor(s, 32, 64); q += __shfl_xor(q, 32, 64);
        if (kgrp == 0) {
            atomicAdd(&sums[col], s);
            atomicAdd(&sumsq[col], q);
        }
    }
}

// ---------------- layer-2 GEMM with fused BN+ReLU on A (coefs from raw stats) ----
// t|root = relu(bn(h_bf)) @ [Wr2|Wt2]^T. A reg-staged (T14 split); W gload_lds.
template<int K>
__global__ __launch_bounds__(512, 4) void gemm2_bn_k(
        const unsigned short* __restrict__ A, const unsigned short* __restrict__ Wa,
        const float* __restrict__ sums, const float* __restrict__ sumsq,
        const float* __restrict__ g, const float* __restrict__ be,
        const float* __restrict__ bias, unsigned short* __restrict__ t_bf,
        float* __restrict__ root, float invN, int Nn) {
    constexpr int BM = 128, BN = 128;
    constexpr int MI = 4, OJ = 2;
    constexpr int NT = K / 32;                 // 8
    __shared__ unsigned short As[2][BM * 32];
    __shared__ unsigned short Bs[2][BN * 32];
    const int tid = threadIdx.x;
    const int w = tid >> 6, l = tid & 63;
    const int wr = w >> 2, wc = w & 3;
    const int lrow = l & 15, kgrp = l >> 4;
    int bx = blockIdx.x;
    bx = (bx & 7) * (gridDim.x >> 3) + (bx >> 3);
    const int m0 = bx * BM;
    const int srow = tid >> 2, sslot = tid & 3;
    const int gslot = sslot ^ ((srow >> 1) & 3);

    auto stageW = [&](int buf, int t) {
        gload_lds16(Wa + (size_t)srow * K + t * 32 + (gslot << 3), &Bs[buf][w * 512]);
    };
    auto loadA = [&](int t) -> bf16x8 {
        return *reinterpret_cast<const bf16x8*>(A + (size_t)(m0 + srow) * K + t * 32 + (gslot << 3));
    };
    auto writeA = [&](int buf, int t, bf16x8 raw) {
        int f0 = t * 32 + (gslot << 3);
        bf16x8 o;
        #pragma unroll
        for (int j = 0; j < 8; ++j) {
            int f = f0 + j;
            float mu = sums[f] * invN;
            float var = sumsq[f] * invN - mu * mu;
            float sc = g[f] * rsqrtf(var + 1e-5f);
            float sh = be[f] - mu * sc;
            float v = bf2f((unsigned short)raw[j]) * sc + sh;
            o[j] = (short)f2bf(fmaxf(v, 0.f));
        }
        *reinterpret_cast<bf16x8*>(&As[buf][tid * 8]) = o;   // same chunk<->(row,slot) map as gload path
    };

    f32x4 acc[MI][OJ];
    #pragma unroll
    for (int i = 0; i < MI; ++i)
        #pragma unroll
        for (int j = 0; j < OJ; ++j) {
            f32x4 z = {0.f, 0.f, 0.f, 0.f};
            acc[i][j] = z;
        }

    // prologue
    {
        bf16x8 r0 = loadA(0);
        stageW(0, 0);
        writeA(0, 0, r0);
    }
    __syncthreads();
    #pragma unroll
    for (int t = 0; t < NT; ++t) {
        const int cur = t & 1;
        bf16x8 nxt;
        if (t + 1 < NT) { nxt = loadA(t + 1); stageW(cur ^ 1, t + 1); }
        bf16x8 a[MI], b[OJ];
        #pragma unroll
        for (int mi = 0; mi < MI; ++mi) {
            int row = wr * 64 + mi * 16 + lrow;
            int slot = kgrp ^ ((row >> 1) & 3);
            a[mi] = *reinterpret_cast<const bf16x8*>(&As[cur][row * 32 + slot * 8]);
        }
        #pragma unroll
        for (int oj = 0; oj < OJ; ++oj) {
            int row = wc * 32 + oj * 16 + lrow;
            int slot = kgrp ^ ((row >> 1) & 3);
            b[oj] = *reinterpret_cast<const bf16x8*>(&Bs[cur][row * 32 + slot * 8]);
        }
        #pragma unroll
        for (int mi = 0; mi < MI; ++mi)
            #pragma unroll
            for (int oj = 0; oj < OJ; ++oj)
                acc[mi][oj] = __builtin_amdgcn_mfma_f32_16x16x32_bf16(
                    a[mi], b[oj], acc[mi][oj], 0, 0, 0);
        if (t + 1 < NT) writeA(cur ^ 1, t + 1, nxt);   // HBM latency hidden under the MFMAs above
        __syncthreads();
    }

    // epilogue: cols 0-63 -> t_bf (bf16, no bias); cols 64-127 -> root f32 + bias
    #pragma unroll
    for (int oj = 0; oj < OJ; ++oj) {
        int col = wc * 32 + oj * 16 + lrow;
        #pragma unroll
        for (int mi = 0; mi < MI; ++mi) {
            #pragma unroll
            for (int r = 0; r < 4; ++r) {
                int row = m0 + wr * 64 + mi * 16 + kgrp * 4 + r;
                if (row < Nn) {
                    if (col < 64)
                        t_bf[(size_t)row * 64 + col] = f2bf(acc[mi][oj][r]);
                    else
                        root[(size_t)row * 64 + (col - 64)] = acc[mi][oj][r] + bias[col - 64];
                }
            }
        }
    }
}

extern "C" void kernel_launch(void* const* d_in, const int* in_sizes, int n_in,
                              void* d_out, int out_size, void* d_ws, size_t ws_size,
                              hipStream_t stream) {
    const float* x   = (const float*)d_in[0];
    const int*   ei  = (const int*)d_in[1];
    const float* ew  = (const float*)d_in[2];
    const float* Wr0 = (const float*)d_in[3];
    const float* br0 = (const float*)d_in[4];
    const float* Wt0 = (const float*)d_in[5];
    const float* g0  = (const float*)d_in[6];
    const float* be0 = (const float*)d_in[7];
    const float* Wr1 = (const float*)d_in[8];
    const float* br1 = (const float*)d_in[9];
    const float* Wt1 = (const float*)d_in[10];
    const float* g1  = (const float*)d_in[11];
    const float* be1 = (const float*)d_in[12];
    const float* Wr2 = (const float*)d_in[13];
    const float* br2 = (const float*)d_in[14];
    const float* Wt2 = (const float*)d_in[15];

    const int E  = in_sizes[2];          // 800000
    const int Nn = in_sizes[0] / 128;    // 50000
    const size_t NP = 50176;             // padded rows (NP/128 % 8 == 0)
    const int* src = ei;
    const int* dst = ei + E;

    // ---- workspace layout ----
    unsigned short* x_bf   = (unsigned short*)d_ws;        // NP*128
    unsigned short* agg_bf = x_bf + NP * 128;              // NP*256
    unsigned short* h0N    = agg_bf + NP * 256;            // NP*256
    unsigned short* h1N    = h0N + NP * 256;               // NP*256 (unused, layout kept)
    unsigned short* h_bf   = h1N + NP * 256;               // NP*256
    unsigned short* t_bf   = h_bf + NP * 256;              // NP*64
    unsigned short* wbf    = t_bf + NP * 64;               // 229376
    unsigned short* Wr0b = wbf;
    unsigned short* Wt0b = wbf + 32768;
    unsigned short* Wr1b = wbf + 65536;
    unsigned short* Wt1b = wbf + 131072;
    unsigned short* W2cat = wbf + 196608;                  // Wr2 | Wt2
    float* root  = (float*)(wbf + 229376);                 // NP*64 f32
    int2*  e_sw  = (int2*)(root + NP * 64);                // E
    float* stats = (float*)(e_sw + E);                     // 4096 f
    int*   counts  = (int*)(stats + 4096);                 // Nn (memset with stats)
    int*   partial = counts + Nn;                          // Nn
    int*   blocksum = partial + Nn;                        // 512
    int*   rank    = blocksum + 512;                       // E
    int*   offsets = rank + E;                             // Nn+1

    dim3 blk(256);
    const int nbScan = (Nn + SCAN_B - 1) / SCAN_B;
    const float invN = 1.0f / (float)Nn;
    const int n4x = Nn * 32;
    const int histBlocks = (E + 255) / 256;
    const int convBlocks = (n4x + 57344 + 255) / 256;

    hipMemsetAsync(stats, 0, (4096 + (size_t)Nn) * sizeof(float), stream);

    // ---- CSR build fused with bf16 conversions ----
    hist_conv_k<<<dim3(histBlocks + convBlocks), blk, 0, stream>>>(
        dst, counts, rank, E, histBlocks,
        x, Wr0, Wt0, Wr1, Wt1, Wr2, Wt2,
        x_bf, Wr0b, Wt0b, Wr1b, Wt1b, W2cat, W2cat + 16384, n4x);
    scan1_k<<<dim3(nbScan), dim3(SCAN_B), 0, stream>>>(counts, partial, blocksum, Nn);
    scan3b_k<<<dim3(nbScan), dim3(SCAN_B), 0, stream>>>(partial, blocksum, offsets, Nn);
    fill2_k<<<dim3(histBlocks), blk, 0, stream>>>(src, dst, ew, offsets, rank, e_sw, E);

    const int gatherBlocks = (Nn * 64 + 255) / 256;   // 12500

    // ---------------- layer 0: K=128 -> 256 ----------------
    gather128_k<<<dim3(gatherBlocks), blk, 0, stream>>>(x_bf, offsets, e_sw, agg_bf, Nn);
    gemm_mfma_k<128, 256, 0><<<dim3(NP / 128, 2), dim3(512), 0, stream>>>(
        agg_bf, Wr0b, x_bf, Wt0b, br0, h_bf, nullptr, stats + 0, stats + 256, Nn);

    // ---------------- fused: gather L1 (inline BN) interleaved with bn_relu ----
    // total blocks: 14584 -> 2083 bn-role (bx%7==6) + 12501 gather-role (>= 12500)
    gather_bn_k<<<dim3(14584), blk, 0, stream>>>(
        h_bf, stats + 0, stats + 256, g0, be0, offsets, e_sw,
        agg_bf, h0N, invN, Nn);

    // ---------------- layer 1: K=256 -> 256 ----------------
    gemm_mfma_k<256, 256, 0><<<dim3(NP / 128, 2), dim3(512), 0, stream>>>(
        agg_bf, Wr1b, h0N, Wt1b, br1, h_bf, nullptr, stats + 1024, stats + 1280, Nn);

    // ---------------- layer 2: transform-first with fused BN+ReLU (coefs inline) ----
    gemm2_bn_k<256><<<dim3(NP / 128, 1), dim3(512), 0, stream>>>(
        h_bf, W2cat, stats + 1024, stats + 1280, g1, be1, br2, t_bf, root, invN, Nn);
    gather_out_k<<<dim3((Nn * 16 + 255) / 256), blk, 0, stream>>>(
        t_bf, root, offsets, e_sw, (float*)d_out, Nn);
}

// Round 14
// 281.344 us; speedup vs baseline: 1.0432x; 1.0432x over previous
//
#include <hip/hip_runtime.h>
#include <cstddef>
#include <cstdint>

#define SCAN_B 512

using bf16x8 = __attribute__((ext_vector_type(8))) short;
using f32x4  = __attribute__((ext_vector_type(4))) float;

__device__ __forceinline__ unsigned short f2bf(float f) {
    unsigned int u = __builtin_bit_cast(unsigned int, f);
    return (unsigned short)((u + 0x7FFFu + ((u >> 16) & 1u)) >> 16);  // RNE
}
__device__ __forceinline__ float bf2f(unsigned short b) {
    unsigned int u = ((unsigned int)b) << 16;
    return __builtin_bit_cast(float, u);
}
__device__ __forceinline__ float i2f(int i) { return __builtin_bit_cast(float, i); }
__device__ __forceinline__ float u2f(unsigned int u) { return __builtin_bit_cast(float, u); }
__device__ __forceinline__ void gload_lds16(const void* g, void* l) {
    __builtin_amdgcn_global_load_lds((const __attribute__((address_space(1))) void*)g,
                                     (__attribute__((address_space(3))) void*)l, 16, 0, 0);
}

// ---------------- CSR hist (+rank) fused with f32->bf16 conversions ----------------
__global__ void hist_conv_k(const int* __restrict__ dst, int* __restrict__ counts,
                            int* __restrict__ rank, int E, int histBlocks,
                            const float* __restrict__ x, const float* __restrict__ Wr0,
                            const float* __restrict__ Wt0, const float* __restrict__ Wr1,
                            const float* __restrict__ Wt1, const float* __restrict__ Wr2,
                            const float* __restrict__ Wt2, unsigned short* __restrict__ x_bf,
                            unsigned short* __restrict__ Wr0b, unsigned short* __restrict__ Wt0b,
                            unsigned short* __restrict__ Wr1b, unsigned short* __restrict__ Wt1b,
                            unsigned short* __restrict__ Wr2b, unsigned short* __restrict__ Wt2b,
                            int n4x) {
    if ((int)blockIdx.x < histBlocks) {
        int e = blockIdx.x * 256 + threadIdx.x;
        if (e < E) rank[e] = atomicAdd(&counts[dst[e]], 1);
        return;
    }
    int j = (blockIdx.x - histBlocks) * 256 + threadIdx.x;
    const float* s;
    unsigned short* d;
    if (j < n4x) { s = x; d = x_bf; }
    else {
        j -= n4x;
        if (j < 8192) { s = Wr0; d = Wr0b; }
        else { j -= 8192;
        if (j < 8192) { s = Wt0; d = Wt0b; }
        else { j -= 8192;
        if (j < 16384) { s = Wr1; d = Wr1b; }
        else { j -= 16384;
        if (j < 16384) { s = Wt1; d = Wt1b; }
        else { j -= 16384;
        if (j < 4096) { s = Wr2; d = Wr2b; }
        else { j -= 4096;
        if (j >= 4096) return;
        s = Wt2; d = Wt2b; } } } } }
    }
    float4 v = reinterpret_cast<const float4*>(s)[j];
    ushort4 o;
    o.x = f2bf(v.x); o.y = f2bf(v.y); o.z = f2bf(v.z); o.w = f2bf(v.w);
    reinterpret_cast<ushort4*>(d)[j] = o;
}

__global__ void scan1_k(const int* __restrict__ counts, int* __restrict__ partial,
                        int* __restrict__ blocksum, int Nn) {
    __shared__ int sh[SCAN_B];
    int i = blockIdx.x * SCAN_B + threadIdx.x;
    int v = (i < Nn) ? counts[i] : 0;
    sh[threadIdx.x] = v;
    __syncthreads();
    for (int off = 1; off < SCAN_B; off <<= 1) {
        int t = (threadIdx.x >= (unsigned)off) ? sh[threadIdx.x - off] : 0;
        __syncthreads();
        sh[threadIdx.x] += t;
        __syncthreads();
    }
    if (i < Nn) partial[i] = sh[threadIdx.x];
    if (threadIdx.x == SCAN_B - 1) blocksum[blockIdx.x] = sh[threadIdx.x];
}

__global__ void scan3b_k(const int* __restrict__ partial, const int* __restrict__ blocksum,
                         int* __restrict__ offsets, int Nn) {
    __shared__ int add_s;
    int bx = blockIdx.x;
    if (threadIdx.x < 64) {
        int s = 0;
        for (int j = threadIdx.x; j < bx; j += 64) s += blocksum[j];
        #pragma unroll
        for (int off = 32; off > 0; off >>= 1) s += __shfl_down(s, off, 64);
        if (threadIdx.x == 0) add_s = s;
    }
    __syncthreads();
    int i = bx * SCAN_B + threadIdx.x;
    if (i >= Nn) return;
    offsets[i + 1] = partial[i] + add_s;
    if (i == 0) offsets[0] = 0;
}

__global__ void fill2_k(const int* __restrict__ src, const int* __restrict__ dst,
                        const float* __restrict__ ew, const int* __restrict__ offsets,
                        const int* __restrict__ rank, int2* __restrict__ e_sw, int E) {
    int e = blockIdx.x * blockDim.x + threadIdx.x;
    if (e >= E) return;
    int pos = offsets[dst[e]] + rank[e];
    e_sw[pos] = make_int2(src[e], __builtin_bit_cast(int, ew[e]));
}

// ---------------- gather F=128 (CSR, bf16, f32 acc, 8-deep ILP) ----------------
__global__ void gather128_k(const unsigned short* __restrict__ x, const int* __restrict__ offsets,
                            const int2* __restrict__ e_sw, unsigned short* __restrict__ agg, int Nn) {
    int wid = __builtin_amdgcn_readfirstlane((blockIdx.x * blockDim.x + threadIdx.x) >> 6);
    int lane = threadIdx.x & 63;
    if (wid >= Nn) return;
    int p = offsets[wid], end = offsets[wid + 1];
    const char* xb = (const char*)x;
    const unsigned loff = lane * 4u;
    float a0 = 0.f, a1 = 0.f;
    for (; p + 8 <= end; p += 8) {
        int2 ee[8];
        #pragma unroll
        for (int i = 0; i < 8; ++i) ee[i] = e_sw[p + i];
        unsigned vv[8];
        #pragma unroll
        for (int i = 0; i < 8; ++i)
            vv[i] = *reinterpret_cast<const unsigned*>(xb + ((unsigned)ee[i].x * 256u + loff));
        #pragma unroll
        for (int i = 0; i < 8; ++i) {
            float w = i2f(ee[i].y);
            a0 += w * u2f(vv[i] << 16); a1 += w * u2f(vv[i] & 0xFFFF0000u);
        }
    }
    for (; p < end; ++p) {
        int2 e0 = e_sw[p];
        unsigned v0 = *reinterpret_cast<const unsigned*>(xb + ((unsigned)e0.x * 256u + loff));
        float w = i2f(e0.y);
        a0 += w * u2f(v0 << 16); a1 += w * u2f(v0 & 0xFFFF0000u);
    }
    unsigned o = (unsigned)f2bf(a0) | ((unsigned)f2bf(a1) << 16);
    *reinterpret_cast<unsigned*>(agg + (size_t)wid * 128 + lane * 2) = o;
}

// ---------------- gather F=256 with inline BN+ReLU (pure gather, no bn pass) ----
__global__ void gather_bn_k(const unsigned short* __restrict__ h_raw,
                            const float* __restrict__ sums, const float* __restrict__ sumsq,
                            const float* __restrict__ g, const float* __restrict__ be,
                            const int* __restrict__ offsets, const int2* __restrict__ e_sw,
                            unsigned short* __restrict__ agg, float invN, int Nn) {
    const int lane = threadIdx.x & 63;
    int wid = __builtin_amdgcn_readfirstlane((blockIdx.x * blockDim.x + threadIdx.x) >> 6);
    if (wid >= Nn) return;
    int f0 = lane * 4;
    float4 sm = *reinterpret_cast<const float4*>(sums + f0);
    float4 sq = *reinterpret_cast<const float4*>(sumsq + f0);
    float4 gg = *reinterpret_cast<const float4*>(g + f0);
    float4 bb = *reinterpret_cast<const float4*>(be + f0);
    float sc0, sc1, sc2, sc3, sh0, sh1, sh2, sh3;
    {
        float mu, var;
        mu = sm.x * invN; var = sq.x * invN - mu * mu; sc0 = gg.x * rsqrtf(var + 1e-5f); sh0 = bb.x - mu * sc0;
        mu = sm.y * invN; var = sq.y * invN - mu * mu; sc1 = gg.y * rsqrtf(var + 1e-5f); sh1 = bb.y - mu * sc1;
        mu = sm.z * invN; var = sq.z * invN - mu * mu; sc2 = gg.z * rsqrtf(var + 1e-5f); sh2 = bb.z - mu * sc2;
        mu = sm.w * invN; var = sq.w * invN - mu * mu; sc3 = gg.w * rsqrtf(var + 1e-5f); sh3 = bb.w - mu * sc3;
    }
    int p = offsets[wid], end = offsets[wid + 1];
    const char* xb = (const char*)h_raw;
    const unsigned loff = lane * 8u;
    float a0 = 0.f, a1 = 0.f, a2 = 0.f, a3 = 0.f;
    for (; p + 8 <= end; p += 8) {
        int2 ee[8];
        #pragma unroll
        for (int i = 0; i < 8; ++i) ee[i] = e_sw[p + i];
        uint2 vv[8];
        #pragma unroll
        for (int i = 0; i < 8; ++i)
            vv[i] = *reinterpret_cast<const uint2*>(xb + ((unsigned)ee[i].x * 512u + loff));
        #pragma unroll
        for (int i = 0; i < 8; ++i) {
            float w = i2f(ee[i].y);
            a0 += w * fmaxf(u2f(vv[i].x << 16) * sc0 + sh0, 0.f);
            a1 += w * fmaxf(u2f(vv[i].x & 0xFFFF0000u) * sc1 + sh1, 0.f);
            a2 += w * fmaxf(u2f(vv[i].y << 16) * sc2 + sh2, 0.f);
            a3 += w * fmaxf(u2f(vv[i].y & 0xFFFF0000u) * sc3 + sh3, 0.f);
        }
    }
    for (; p < end; ++p) {
        int2 e0 = e_sw[p];
        uint2 v0 = *reinterpret_cast<const uint2*>(xb + ((unsigned)e0.x * 512u + loff));
        float w = i2f(e0.y);
        a0 += w * fmaxf(u2f(v0.x << 16) * sc0 + sh0, 0.f);
        a1 += w * fmaxf(u2f(v0.x & 0xFFFF0000u) * sc1 + sh1, 0.f);
        a2 += w * fmaxf(u2f(v0.y << 16) * sc2 + sh2, 0.f);
        a3 += w * fmaxf(u2f(v0.y & 0xFFFF0000u) * sc3 + sh3, 0.f);
    }
    uint2 o;
    o.x = (unsigned)f2bf(a0) | ((unsigned)f2bf(a1) << 16);
    o.y = (unsigned)f2bf(a2) | ((unsigned)f2bf(a3) << 16);
    *reinterpret_cast<uint2*>(agg + (size_t)wid * 256 + lane * 4) = o;
}

// ---- final: out[node] = root[node] + sum_e w * t[src], F=64, 16 lanes/node ----
__global__ void gather_out_k(const unsigned short* __restrict__ t, const float* __restrict__ root,
                             const int* __restrict__ offsets, const int2* __restrict__ e_sw,
                             float* __restrict__ out, int Nn) {
    int gt = blockIdx.x * blockDim.x + threadIdx.x;
    int node = gt >> 4;
    int li = gt & 15;
    if (node >= Nn) return;
    int p = offsets[node], end = offsets[node + 1];
    const char* tb = (const char*)t;
    const unsigned loff = li * 8u;
    float a0 = 0.f, a1 = 0.f, a2 = 0.f, a3 = 0.f;
    for (; p + 8 <= end; p += 8) {
        int2 ee[8];
        #pragma unroll
        for (int i = 0; i < 8; ++i) ee[i] = e_sw[p + i];
        uint2 vv[8];
        #pragma unroll
        for (int i = 0; i < 8; ++i)
            vv[i] = *reinterpret_cast<const uint2*>(tb + ((unsigned)ee[i].x * 128u + loff));
        #pragma unroll
        for (int i = 0; i < 8; ++i) {
            float w = i2f(ee[i].y);
            a0 += w * u2f(vv[i].x << 16); a1 += w * u2f(vv[i].x & 0xFFFF0000u);
            a2 += w * u2f(vv[i].y << 16); a3 += w * u2f(vv[i].y & 0xFFFF0000u);
        }
    }
    for (; p < end; ++p) {
        int2 e0 = e_sw[p];
        uint2 v0 = *reinterpret_cast<const uint2*>(tb + ((unsigned)e0.x * 128u + loff));
        float w = i2f(e0.y);
        a0 += w * u2f(v0.x << 16); a1 += w * u2f(v0.x & 0xFFFF0000u);
        a2 += w * u2f(v0.y << 16); a3 += w * u2f(v0.y & 0xFFFF0000u);
    }
    float4 r = *reinterpret_cast<const float4*>(root + (size_t)node * 64 + li * 4);
    float4 o = make_float4(r.x + a0, r.y + a1, r.z + a2, r.w + a3);
    *reinterpret_cast<float4*>(out + (size_t)node * 64 + li * 4) = o;
}

// ---------------- L0 GEMM: 8 waves, BK=32, dbuf stage-early, 4 blocks/CU ----
// h = agg@Wr0.T + x@Wt0.T + br0 -> bf16 h_bf + fused col stats.
template<int K, int O>
__global__ __launch_bounds__(512, 4) void gemm0_k(
        const unsigned short* __restrict__ A, const unsigned short* __restrict__ Wa,
        const unsigned short* __restrict__ X, const unsigned short* __restrict__ Wb,
        const float* __restrict__ bias, unsigned short* __restrict__ out_bf,
        float* __restrict__ sums, float* __restrict__ sumsq, int Nn) {
    constexpr int BM = 128, BN = 128;
    constexpr int MI = 4, OJ = 2;
    constexpr int KSTEPS = K / 32;
    constexpr int NT = 2 * KSTEPS;
    __shared__ unsigned short As[2][BM * 32];
    __shared__ unsigned short Bs[2][BN * 32];
    const int tid = threadIdx.x;
    const int w = tid >> 6, l = tid & 63;
    const int wr = w >> 2, wc = w & 3;
    const int lrow = l & 15, kgrp = l >> 4;
    int bx = blockIdx.x;
    bx = (bx & 7) * (gridDim.x >> 3) + (bx >> 3);
    const int m0 = bx * BM;
    const int n0 = blockIdx.y * BN;
    const int srow = tid >> 2, sslot = tid & 3;
    const int gslot = sslot ^ ((srow >> 1) & 3);

    auto stage = [&](int buf, int t) {
        int ph = t / KSTEPS;
        int k0 = (t % KSTEPS) * 32;
        const unsigned short* Ap = ph ? X : A;
        const unsigned short* Wp = ph ? Wb : Wa;
        gload_lds16(Ap + (size_t)(m0 + srow) * K + k0 + (gslot << 3), &As[buf][w * 512]);
        gload_lds16(Wp + (size_t)(n0 + srow) * K + k0 + (gslot << 3), &Bs[buf][w * 512]);
    };

    f32x4 acc[MI][OJ];
    #pragma unroll
    for (int i = 0; i < MI; ++i)
        #pragma unroll
        for (int j = 0; j < OJ; ++j) {
            f32x4 z = {0.f, 0.f, 0.f, 0.f};
            acc[i][j] = z;
        }

    stage(0, 0);
    __syncthreads();
    #pragma unroll
    for (int t = 0; t < NT; ++t) {
        const int cur = t & 1;
        if (t + 1 < NT) stage(cur ^ 1, t + 1);
        bf16x8 a[MI], b[OJ];
        #pragma unroll
        for (int mi = 0; mi < MI; ++mi) {
            int row = wr * 64 + mi * 16 + lrow;
            int slot = kgrp ^ ((row >> 1) & 3);
            a[mi] = *reinterpret_cast<const bf16x8*>(&As[cur][row * 32 + slot * 8]);
        }
        #pragma unroll
        for (int oj = 0; oj < OJ; ++oj) {
            int row = wc * 32 + oj * 16 + lrow;
            int slot = kgrp ^ ((row >> 1) & 3);
            b[oj] = *reinterpret_cast<const bf16x8*>(&Bs[cur][row * 32 + slot * 8]);
        }
        #pragma unroll
        for (int mi = 0; mi < MI; ++mi)
            #pragma unroll
            for (int oj = 0; oj < OJ; ++oj)
                acc[mi][oj] = __builtin_amdgcn_mfma_f32_16x16x32_bf16(
                    a[mi], b[oj], acc[mi][oj], 0, 0, 0);
        __syncthreads();
    }

    #pragma unroll
    for (int oj = 0; oj < OJ; ++oj) {
        int col = n0 + wc * 32 + oj * 16 + lrow;
        float bcol = bias[col];
        float s = 0.f, q = 0.f;
        #pragma unroll
        for (int mi = 0; mi < MI; ++mi) {
            #pragma unroll
            for (int r = 0; r < 4; ++r) {
                int row = m0 + wr * 64 + mi * 16 + kgrp * 4 + r;
                float v = acc[mi][oj][r] + bcol;
                if (row < Nn) {
                    out_bf[(size_t)row * O + col] = f2bf(v);
                    s += v; q += v * v;
                }
            }
        }
        s += __shfl_xor(s, 16, 64); q += __shfl_xor(q, 16, 64);
        s += __shfl_xor(s, 32, 64); q += __shfl_xor(q, 32, 64);
        if (kgrp == 0) {
            atomicAdd(&sums[col], s);
            atomicAdd(&sumsq[col], q);
        }
    }
}

// ---------------- L1 GEMM with fused BN+ReLU on the X (root) operand ----------------
// h1 = agg@Wr1.T + relu(bn0(h_raw))@Wt1.T + br1 -> bf16 h1N + fused col stats.
// A-phase (t<KS): agg via global_load_lds. X-phase (t>=KS): h_raw reg-staged
// (T14 split: load before compute, BN+ds_write after), coefs from LDS prologue.
template<int K, int O>
__global__ __launch_bounds__(512, 4) void gemm1_bn_k(
        const unsigned short* __restrict__ A, const unsigned short* __restrict__ Wa,
        const unsigned short* __restrict__ X, const unsigned short* __restrict__ Wb,
        const float* __restrict__ sums0, const float* __restrict__ sumsq0,
        const float* __restrict__ g0, const float* __restrict__ be0,
        const float* __restrict__ bias, unsigned short* __restrict__ out_bf,
        float* __restrict__ sums1, float* __restrict__ sumsq1, float invN, int Nn) {
    constexpr int BM = 128, BN = 128;
    constexpr int MI = 4, OJ = 2;
    constexpr int KSTEPS = K / 32;                // 8
    constexpr int NT = 2 * KSTEPS;                // 16
    __shared__ unsigned short As[2][BM * 32];
    __shared__ unsigned short Bs[2][BN * 32];
    __shared__ float scs[256], shs[256];
    const int tid = threadIdx.x;
    const int w = tid >> 6, l = tid & 63;
    const int wr = w >> 2, wc = w & 3;
    const int lrow = l & 15, kgrp = l >> 4;
    int bx = blockIdx.x;
    bx = (bx & 7) * (gridDim.x >> 3) + (bx >> 3);
    const int m0 = bx * BM;
    const int n0 = blockIdx.y * BN;
    const int srow = tid >> 2, sslot = tid & 3;
    const int gslot = sslot ^ ((srow >> 1) & 3);

    auto stageB = [&](int buf, int t) {
        int k0 = (t % KSTEPS) * 32;
        const unsigned short* Wp = (t < KSTEPS) ? Wa : Wb;
        gload_lds16(Wp + (size_t)(n0 + srow) * K + k0 + (gslot << 3), &Bs[buf][w * 512]);
    };
    auto stageA = [&](int buf, int t) {   // A-phase only
        int k0 = t * 32;
        gload_lds16(A + (size_t)(m0 + srow) * K + k0 + (gslot << 3), &As[buf][w * 512]);
    };
    auto loadX = [&](int t) -> bf16x8 {   // X-phase only
        int k0 = (t - KSTEPS) * 32;
        return *reinterpret_cast<const bf16x8*>(X + (size_t)(m0 + srow) * K + k0 + (gslot << 3));
    };
    auto writeX = [&](int buf, int t, bf16x8 raw) {
        int f0 = (t - KSTEPS) * 32 + (gslot << 3);
        bf16x8 o;
        #pragma unroll
        for (int j = 0; j < 8; ++j) {
            float v = bf2f((unsigned short)raw[j]) * scs[f0 + j] + shs[f0 + j];
            o[j] = (short)f2bf(fmaxf(v, 0.f));
        }
        *reinterpret_cast<bf16x8*>(&As[buf][tid * 8]) = o;   // same chunk<->(row,slot) map
    };

    // coef prologue: 256 features -> LDS (drained by the first __syncthreads)
    if (tid < 256) {
        float mu = sums0[tid] * invN;
        float var = sumsq0[tid] * invN - mu * mu;
        float sc = g0[tid] * rsqrtf(var + 1e-5f);
        scs[tid] = sc;
        shs[tid] = be0[tid] - mu * sc;
    }

    f32x4 acc[MI][OJ];
    #pragma unroll
    for (int i = 0; i < MI; ++i)
        #pragma unroll
        for (int j = 0; j < OJ; ++j) {
            f32x4 z = {0.f, 0.f, 0.f, 0.f};
            acc[i][j] = z;
        }

    stageB(0, 0);
    stageA(0, 0);
    __syncthreads();
    #pragma unroll
    for (int t = 0; t < NT; ++t) {
        const int cur = t & 1;
        bf16x8 nxt;
        const bool nxtReg = (t + 1 < NT) && (t + 1 >= KSTEPS);
        if (t + 1 < NT) {
            stageB(cur ^ 1, t + 1);
            if (t + 1 < KSTEPS) stageA(cur ^ 1, t + 1);
            else nxt = loadX(t + 1);
        }
        bf16x8 a[MI], b[OJ];
        #pragma unroll
        for (int mi = 0; mi < MI; ++mi) {
            int row = wr * 64 + mi * 16 + lrow;
            int slot = kgrp ^ ((row >> 1) & 3);
            a[mi] = *reinterpret_cast<const bf16x8*>(&As[cur][row * 32 + slot * 8]);
        }
        #pragma unroll
        for (int oj = 0; oj < OJ; ++oj) {
            int row = wc * 32 + oj * 16 + lrow;
            int slot = kgrp ^ ((row >> 1) & 3);
            b[oj] = *reinterpret_cast<const bf16x8*>(&Bs[cur][row * 32 + slot * 8]);
        }
        #pragma unroll
        for (int mi = 0; mi < MI; ++mi)
            #pragma unroll
            for (int oj = 0; oj < OJ; ++oj)
                acc[mi][oj] = __builtin_amdgcn_mfma_f32_16x16x32_bf16(
                    a[mi], b[oj], acc[mi][oj], 0, 0, 0);
        if (nxtReg) writeX(cur ^ 1, t + 1, nxt);   // HBM latency hidden under MFMAs
        __syncthreads();                            // drains vmcnt + lgkmcnt
    }

    #pragma unroll
    for (int oj = 0; oj < OJ; ++oj) {
        int col = n0 + wc * 32 + oj * 16 + lrow;
        float bcol = bias[col];
        float s = 0.f, q = 0.f;
        #pragma unroll
        for (int mi = 0; mi < MI; ++mi) {
            #pragma unroll
            for (int r = 0; r < 4; ++r) {
                int row = m0 + wr * 64 + mi * 16 + kgrp * 4 + r;
                float v = acc[mi][oj][r] + bcol;
                if (row < Nn) {
                    out_bf[(size_t)row * O + col] = f2bf(v);
                    s += v; q += v * v;
                }
            }
        }
        s += __shfl_xor(s, 16, 64); q += __shfl_xor(q, 16, 64);
        s += __shfl_xor(s, 32, 64); q += __shfl_xor(q, 32, 64);
        if (kgrp == 0) {
            atomicAdd(&sums1[col], s);
            atomicAdd(&sumsq1[col], q);
        }
    }
}

// ---------------- layer-2 GEMM: t|root = relu(bn1(h1N)) @ [Wr2|Wt2]^T ----------------
// A reg-staged with BN (coefs from LDS prologue); W via global_load_lds.
template<int K>
__global__ __launch_bounds__(512, 4) void gemm2_bn_k(
        const unsigned short* __restrict__ A, const unsigned short* __restrict__ Wa,
        const float* __restrict__ sums, const float* __restrict__ sumsq,
        const float* __restrict__ g, const float* __restrict__ be,
        const float* __restrict__ bias, unsigned short* __restrict__ t_bf,
        float* __restrict__ root, float invN, int Nn) {
    constexpr int BM = 128, BN = 128;
    constexpr int MI = 4, OJ = 2;
    constexpr int NT = K / 32;                 // 8
    __shared__ unsigned short As[2][BM * 32];
    __shared__ unsigned short Bs[2][BN * 32];
    __shared__ float scs[256], shs[256];
    const int tid = threadIdx.x;
    const int w = tid >> 6, l = tid & 63;
    const int wr = w >> 2, wc = w & 3;
    const int lrow = l & 15, kgrp = l >> 4;
    int bx = blockIdx.x;
    bx = (bx & 7) * (gridDim.x >> 3) + (bx >> 3);
    const int m0 = bx * BM;
    const int srow = tid >> 2, sslot = tid & 3;
    const int gslot = sslot ^ ((srow >> 1) & 3);

    auto stageW = [&](int buf, int t) {
        gload_lds16(Wa + (size_t)srow * K + t * 32 + (gslot << 3), &Bs[buf][w * 512]);
    };
    auto loadA = [&](int t) -> bf16x8 {
        return *reinterpret_cast<const bf16x8*>(A + (size_t)(m0 + srow) * K + t * 32 + (gslot << 3));
    };
    auto writeA = [&](int buf, int t, bf16x8 raw) {
        int f0 = t * 32 + (gslot << 3);
        bf16x8 o;
        #pragma unroll
        for (int j = 0; j < 8; ++j) {
            float v = bf2f((unsigned short)raw[j]) * scs[f0 + j] + shs[f0 + j];
            o[j] = (short)f2bf(fmaxf(v, 0.f));
        }
        *reinterpret_cast<bf16x8*>(&As[buf][tid * 8]) = o;
    };

    if (tid < 256) {
        float mu = sums[tid] * invN;
        float var = sumsq[tid] * invN - mu * mu;
        float sc = g[tid] * rsqrtf(var + 1e-5f);
        scs[tid] = sc;
        shs[tid] = be[tid] - mu * sc;
    }

    f32x4 acc[MI][OJ];
    #pragma unroll
    for (int i = 0; i < MI; ++i)
        #pragma unroll
        for (int j = 0; j < OJ; ++j) {
            f32x4 z = {0.f, 0.f, 0.f, 0.f};
            acc[i][j] = z;
        }

    // prologue (writeA needs scs -> barrier first, then write, then barrier)
    bf16x8 r0 = loadA(0);
    stageW(0, 0);
    __syncthreads();            // scs/shs ready
    writeA(0, 0, r0);
    __syncthreads();            // As[0] ready (lgkmcnt+vmcnt drained)
    #pragma unroll
    for (int t = 0; t < NT; ++t) {
        const int cur = t & 1;
        bf16x8 nxt;
        if (t + 1 < NT) { nxt = loadA(t + 1); stageW(cur ^ 1, t + 1); }
        bf16x8 a[MI], b[OJ];
        #pragma unroll
        for (int mi = 0; mi < MI; ++mi) {
            int row = wr * 64 + mi * 16 + lrow;
            int slot = kgrp ^ ((row >> 1) & 3);
            a[mi] = *reinterpret_cast<const bf16x8*>(&As[cur][row * 32 + slot * 8]);
        }
        #pragma unroll
        for (int oj = 0; oj < OJ; ++oj) {
            int row = wc * 32 + oj * 16 + lrow;
            int slot = kgrp ^ ((row >> 1) & 3);
            b[oj] = *reinterpret_cast<const bf16x8*>(&Bs[cur][row * 32 + slot * 8]);
        }
        #pragma unroll
        for (int mi = 0; mi < MI; ++mi)
            #pragma unroll
            for (int oj = 0; oj < OJ; ++oj)
                acc[mi][oj] = __builtin_amdgcn_mfma_f32_16x16x32_bf16(
                    a[mi], b[oj], acc[mi][oj], 0, 0, 0);
        if (t + 1 < NT) writeA(cur ^ 1, t + 1, nxt);
        __syncthreads();
    }

    #pragma unroll
    for (int oj = 0; oj < OJ; ++oj) {
        int col = wc * 32 + oj * 16 + lrow;
        #pragma unroll
        for (int mi = 0; mi < MI; ++mi) {
            #pragma unroll
            for (int r = 0; r < 4; ++r) {
                int row = m0 + wr * 64 + mi * 16 + kgrp * 4 + r;
                if (row < Nn) {
                    if (col < 64)
                        t_bf[(size_t)row * 64 + col] = f2bf(acc[mi][oj][r]);
                    else
                        root[(size_t)row * 64 + (col - 64)] = acc[mi][oj][r] + bias[col - 64];
                }
            }
        }
    }
}

extern "C" void kernel_launch(void* const* d_in, const int* in_sizes, int n_in,
                              void* d_out, int out_size, void* d_ws, size_t ws_size,
                              hipStream_t stream) {
    const float* x   = (const float*)d_in[0];
    const int*   ei  = (const int*)d_in[1];
    const float* ew  = (const float*)d_in[2];
    const float* Wr0 = (const float*)d_in[3];
    const float* br0 = (const float*)d_in[4];
    const float* Wt0 = (const float*)d_in[5];
    const float* g0  = (const float*)d_in[6];
    const float* be0 = (const float*)d_in[7];
    const float* Wr1 = (const float*)d_in[8];
    const float* br1 = (const float*)d_in[9];
    const float* Wt1 = (const float*)d_in[10];
    const float* g1  = (const float*)d_in[11];
    const float* be1 = (const float*)d_in[12];
    const float* Wr2 = (const float*)d_in[13];
    const float* br2 = (const float*)d_in[14];
    const float* Wt2 = (const float*)d_in[15];

    const int E  = in_sizes[2];          // 800000
    const int Nn = in_sizes[0] / 128;    // 50000
    const size_t NP = 50176;             // padded rows (NP/128 % 8 == 0)
    const int* src = ei;
    const int* dst = ei + E;

    // ---- workspace layout ----
    unsigned short* x_bf   = (unsigned short*)d_ws;        // NP*128
    unsigned short* agg_bf = x_bf + NP * 128;              // NP*256
    unsigned short* h1N    = agg_bf + NP * 256;            // NP*256 (L1 raw out)
    unsigned short* h_bf   = h1N + NP * 256;               // NP*256 (L0 raw out)
    unsigned short* t_bf   = h_bf + NP * 256;              // NP*64
    unsigned short* wbf    = t_bf + NP * 64;               // 229376
    unsigned short* Wr0b = wbf;
    unsigned short* Wt0b = wbf + 32768;
    unsigned short* Wr1b = wbf + 65536;
    unsigned short* Wt1b = wbf + 131072;
    unsigned short* W2cat = wbf + 196608;                  // Wr2 | Wt2
    float* root  = (float*)(wbf + 229376);                 // NP*64 f32
    int2*  e_sw  = (int2*)(root + NP * 64);                // E
    float* stats = (float*)(e_sw + E);                     // 4096 f
    int*   counts  = (int*)(stats + 4096);                 // Nn (memset with stats)
    int*   partial = counts + Nn;                          // Nn
    int*   blocksum = partial + Nn;                        // 512
    int*   rank    = blocksum + 512;                       // E
    int*   offsets = rank + E;                             // Nn+1

    dim3 blk(256);
    const int nbScan = (Nn + SCAN_B - 1) / SCAN_B;
    const float invN = 1.0f / (float)Nn;
    const int n4x = Nn * 32;
    const int histBlocks = (E + 255) / 256;
    const int convBlocks = (n4x + 57344 + 255) / 256;

    hipMemsetAsync(stats, 0, (4096 + (size_t)Nn) * sizeof(float), stream);

    // ---- CSR build fused with bf16 conversions ----
    hist_conv_k<<<dim3(histBlocks + convBlocks), blk, 0, stream>>>(
        dst, counts, rank, E, histBlocks,
        x, Wr0, Wt0, Wr1, Wt1, Wr2, Wt2,
        x_bf, Wr0b, Wt0b, Wr1b, Wt1b, W2cat, W2cat + 16384, n4x);
    scan1_k<<<dim3(nbScan), dim3(SCAN_B), 0, stream>>>(counts, partial, blocksum, Nn);
    scan3b_k<<<dim3(nbScan), dim3(SCAN_B), 0, stream>>>(partial, blocksum, offsets, Nn);
    fill2_k<<<dim3(histBlocks), blk, 0, stream>>>(src, dst, ew, offsets, rank, e_sw, E);

    const int gatherBlocks = (Nn * 64 + 255) / 256;   // 12500

    // ---------------- layer 0: K=128 -> 256 ----------------
    gather128_k<<<dim3(gatherBlocks), blk, 0, stream>>>(x_bf, offsets, e_sw, agg_bf, Nn);
    gemm0_k<128, 256><<<dim3(NP / 128, 2), dim3(512), 0, stream>>>(
        agg_bf, Wr0b, x_bf, Wt0b, br0, h_bf, stats + 0, stats + 256, Nn);

    // ---------------- layer 1: gather (inline BN0) then dual GEMM (X fused BN0) ----
    gather_bn_k<<<dim3(gatherBlocks), blk, 0, stream>>>(
        h_bf, stats + 0, stats + 256, g0, be0, offsets, e_sw, agg_bf, invN, Nn);
    gemm1_bn_k<256, 256><<<dim3(NP / 128, 2), dim3(512), 0, stream>>>(
        agg_bf, Wr1b, h_bf, Wt1b, stats + 0, stats + 256, g0, be0,
        br1, h1N, stats + 1024, stats + 1280, invN, Nn);

    // ---------------- layer 2: transform-first with fused BN1 ----------------
    gemm2_bn_k<256><<<dim3(NP / 128, 1), dim3(512), 0, stream>>>(
        h1N, W2cat, stats + 1024, stats + 1280, g1, be1, br2, t_bf, root, invN, Nn);
    gather_out_k<<<dim3((Nn * 16 + 255) / 256), blk, 0, stream>>>(
        t_bf, root, offsets, e_sw, (float*)d_out, Nn);
}

// Round 15
// 271.343 us; speedup vs baseline: 1.0816x; 1.0369x over previous
//
#include <hip/hip_runtime.h>
#include <cstddef>
#include <cstdint>

#define SCAN_B 512

using bf16x8 = __attribute__((ext_vector_type(8))) short;
using f32x4  = __attribute__((ext_vector_type(4))) float;

__device__ __forceinline__ unsigned short f2bf(float f) {
    unsigned int u = __builtin_bit_cast(unsigned int, f);
    return (unsigned short)((u + 0x7FFFu + ((u >> 16) & 1u)) >> 16);  // RNE
}
__device__ __forceinline__ float bf2f(unsigned short b) {
    unsigned int u = ((unsigned int)b) << 16;
    return __builtin_bit_cast(float, u);
}
__device__ __forceinline__ float i2f(int i) { return __builtin_bit_cast(float, i); }
__device__ __forceinline__ float u2f(unsigned int u) { return __builtin_bit_cast(float, u); }
__device__ __forceinline__ void gload_lds16(const void* g, void* l) {
    __builtin_amdgcn_global_load_lds((const __attribute__((address_space(1))) void*)g,
                                     (__attribute__((address_space(3))) void*)l, 16, 0, 0);
}

// ---------------- CSR hist (+rank) fused with f32->bf16 conversions ----------------
__global__ void hist_conv_k(const int* __restrict__ dst, int* __restrict__ counts,
                            int* __restrict__ rank, int E, int histBlocks,
                            const float* __restrict__ x, const float* __restrict__ Wr0,
                            const float* __restrict__ Wt0, const float* __restrict__ Wr1,
                            const float* __restrict__ Wt1, const float* __restrict__ Wr2,
                            const float* __restrict__ Wt2, unsigned short* __restrict__ x_bf,
                            unsigned short* __restrict__ Wr0b, unsigned short* __restrict__ Wt0b,
                            unsigned short* __restrict__ Wr1b, unsigned short* __restrict__ Wt1b,
                            unsigned short* __restrict__ Wr2b, unsigned short* __restrict__ Wt2b,
                            int n4x) {
    if ((int)blockIdx.x < histBlocks) {
        int e = blockIdx.x * 256 + threadIdx.x;
        if (e < E) rank[e] = atomicAdd(&counts[dst[e]], 1);
        return;
    }
    int j = (blockIdx.x - histBlocks) * 256 + threadIdx.x;
    const float* s;
    unsigned short* d;
    if (j < n4x) { s = x; d = x_bf; }
    else {
        j -= n4x;
        if (j < 8192) { s = Wr0; d = Wr0b; }
        else { j -= 8192;
        if (j < 8192) { s = Wt0; d = Wt0b; }
        else { j -= 8192;
        if (j < 16384) { s = Wr1; d = Wr1b; }
        else { j -= 16384;
        if (j < 16384) { s = Wt1; d = Wt1b; }
        else { j -= 16384;
        if (j < 4096) { s = Wr2; d = Wr2b; }
        else { j -= 4096;
        if (j >= 4096) return;
        s = Wt2; d = Wt2b; } } } } }
    }
    float4 v = reinterpret_cast<const float4*>(s)[j];
    ushort4 o;
    o.x = f2bf(v.x); o.y = f2bf(v.y); o.z = f2bf(v.z); o.w = f2bf(v.w);
    reinterpret_cast<ushort4*>(d)[j] = o;
}

__global__ void scan1_k(const int* __restrict__ counts, int* __restrict__ partial,
                        int* __restrict__ blocksum, int Nn) {
    __shared__ int sh[SCAN_B];
    int i = blockIdx.x * SCAN_B + threadIdx.x;
    int v = (i < Nn) ? counts[i] : 0;
    sh[threadIdx.x] = v;
    __syncthreads();
    for (int off = 1; off < SCAN_B; off <<= 1) {
        int t = (threadIdx.x >= (unsigned)off) ? sh[threadIdx.x - off] : 0;
        __syncthreads();
        sh[threadIdx.x] += t;
        __syncthreads();
    }
    if (i < Nn) partial[i] = sh[threadIdx.x];
    if (threadIdx.x == SCAN_B - 1) blocksum[blockIdx.x] = sh[threadIdx.x];
}

__global__ void scan3b_k(const int* __restrict__ partial, const int* __restrict__ blocksum,
                         int* __restrict__ offsets, int Nn) {
    __shared__ int add_s;
    int bx = blockIdx.x;
    if (threadIdx.x < 64) {
        int s = 0;
        for (int j = threadIdx.x; j < bx; j += 64) s += blocksum[j];
        #pragma unroll
        for (int off = 32; off > 0; off >>= 1) s += __shfl_down(s, off, 64);
        if (threadIdx.x == 0) add_s = s;
    }
    __syncthreads();
    int i = bx * SCAN_B + threadIdx.x;
    if (i >= Nn) return;
    offsets[i + 1] = partial[i] + add_s;
    if (i == 0) offsets[0] = 0;
}

__global__ void fill2_k(const int* __restrict__ src, const int* __restrict__ dst,
                        const float* __restrict__ ew, const int* __restrict__ offsets,
                        const int* __restrict__ rank, int2* __restrict__ e_sw, int E) {
    int e = blockIdx.x * blockDim.x + threadIdx.x;
    if (e >= E) return;
    int pos = offsets[dst[e]] + rank[e];
    e_sw[pos] = make_int2(src[e], __builtin_bit_cast(int, ew[e]));
}

// ---------------- gather F=128 (CSR, bf16, f32 acc, 8-deep ILP) ----------------
__global__ void gather128_k(const unsigned short* __restrict__ x, const int* __restrict__ offsets,
                            const int2* __restrict__ e_sw, unsigned short* __restrict__ agg, int Nn) {
    int wid = __builtin_amdgcn_readfirstlane((blockIdx.x * blockDim.x + threadIdx.x) >> 6);
    int lane = threadIdx.x & 63;
    if (wid >= Nn) return;
    int p = offsets[wid], end = offsets[wid + 1];
    const char* xb = (const char*)x;
    const unsigned loff = lane * 4u;
    float a0 = 0.f, a1 = 0.f;
    for (; p + 8 <= end; p += 8) {
        int2 ee[8];
        #pragma unroll
        for (int i = 0; i < 8; ++i) ee[i] = e_sw[p + i];
        unsigned vv[8];
        #pragma unroll
        for (int i = 0; i < 8; ++i)
            vv[i] = *reinterpret_cast<const unsigned*>(xb + ((unsigned)ee[i].x * 256u + loff));
        #pragma unroll
        for (int i = 0; i < 8; ++i) {
            float w = i2f(ee[i].y);
            a0 += w * u2f(vv[i] << 16); a1 += w * u2f(vv[i] & 0xFFFF0000u);
        }
    }
    for (; p < end; ++p) {
        int2 e0 = e_sw[p];
        unsigned v0 = *reinterpret_cast<const unsigned*>(xb + ((unsigned)e0.x * 256u + loff));
        float w = i2f(e0.y);
        a0 += w * u2f(v0 << 16); a1 += w * u2f(v0 & 0xFFFF0000u);
    }
    unsigned o = (unsigned)f2bf(a0) | ((unsigned)f2bf(a1) << 16);
    *reinterpret_cast<unsigned*>(agg + (size_t)wid * 128 + lane * 2) = o;
}

// ---------------- gather F=256 with inline BN+ReLU ----------------
__global__ void gather_bn_k(const unsigned short* __restrict__ h_raw,
                            const float* __restrict__ sums, const float* __restrict__ sumsq,
                            const float* __restrict__ g, const float* __restrict__ be,
                            const int* __restrict__ offsets, const int2* __restrict__ e_sw,
                            unsigned short* __restrict__ agg, float invN, int Nn) {
    const int lane = threadIdx.x & 63;
    int wid = __builtin_amdgcn_readfirstlane((blockIdx.x * blockDim.x + threadIdx.x) >> 6);
    if (wid >= Nn) return;
    int f0 = lane * 4;
    float4 sm = *reinterpret_cast<const float4*>(sums + f0);
    float4 sq = *reinterpret_cast<const float4*>(sumsq + f0);
    float4 gg = *reinterpret_cast<const float4*>(g + f0);
    float4 bb = *reinterpret_cast<const float4*>(be + f0);
    float sc0, sc1, sc2, sc3, sh0, sh1, sh2, sh3;
    {
        float mu, var;
        mu = sm.x * invN; var = sq.x * invN - mu * mu; sc0 = gg.x * rsqrtf(var + 1e-5f); sh0 = bb.x - mu * sc0;
        mu = sm.y * invN; var = sq.y * invN - mu * mu; sc1 = gg.y * rsqrtf(var + 1e-5f); sh1 = bb.y - mu * sc1;
        mu = sm.z * invN; var = sq.z * invN - mu * mu; sc2 = gg.z * rsqrtf(var + 1e-5f); sh2 = bb.z - mu * sc2;
        mu = sm.w * invN; var = sq.w * invN - mu * mu; sc3 = gg.w * rsqrtf(var + 1e-5f); sh3 = bb.w - mu * sc3;
    }
    int p = offsets[wid], end = offsets[wid + 1];
    const char* xb = (const char*)h_raw;
    const unsigned loff = lane * 8u;
    float a0 = 0.f, a1 = 0.f, a2 = 0.f, a3 = 0.f;
    for (; p + 8 <= end; p += 8) {
        int2 ee[8];
        #pragma unroll
        for (int i = 0; i < 8; ++i) ee[i] = e_sw[p + i];
        uint2 vv[8];
        #pragma unroll
        for (int i = 0; i < 8; ++i)
            vv[i] = *reinterpret_cast<const uint2*>(xb + ((unsigned)ee[i].x * 512u + loff));
        #pragma unroll
        for (int i = 0; i < 8; ++i) {
            float w = i2f(ee[i].y);
            a0 += w * fmaxf(u2f(vv[i].x << 16) * sc0 + sh0, 0.f);
            a1 += w * fmaxf(u2f(vv[i].x & 0xFFFF0000u) * sc1 + sh1, 0.f);
            a2 += w * fmaxf(u2f(vv[i].y << 16) * sc2 + sh2, 0.f);
            a3 += w * fmaxf(u2f(vv[i].y & 0xFFFF0000u) * sc3 + sh3, 0.f);
        }
    }
    for (; p < end; ++p) {
        int2 e0 = e_sw[p];
        uint2 v0 = *reinterpret_cast<const uint2*>(xb + ((unsigned)e0.x * 512u + loff));
        float w = i2f(e0.y);
        a0 += w * fmaxf(u2f(v0.x << 16) * sc0 + sh0, 0.f);
        a1 += w * fmaxf(u2f(v0.x & 0xFFFF0000u) * sc1 + sh1, 0.f);
        a2 += w * fmaxf(u2f(v0.y << 16) * sc2 + sh2, 0.f);
        a3 += w * fmaxf(u2f(v0.y & 0xFFFF0000u) * sc3 + sh3, 0.f);
    }
    uint2 o;
    o.x = (unsigned)f2bf(a0) | ((unsigned)f2bf(a1) << 16);
    o.y = (unsigned)f2bf(a2) | ((unsigned)f2bf(a3) << 16);
    *reinterpret_cast<uint2*>(agg + (size_t)wid * 256 + lane * 4) = o;
}

// ---- final: out[node] = root[node] + sum_e w * t[src], F=64, 16 lanes/node ----
__global__ void gather_out_k(const unsigned short* __restrict__ t, const float* __restrict__ root,
                             const int* __restrict__ offsets, const int2* __restrict__ e_sw,
                             float* __restrict__ out, int Nn) {
    int gt = blockIdx.x * blockDim.x + threadIdx.x;
    int node = gt >> 4;
    int li = gt & 15;
    if (node >= Nn) return;
    int p = offsets[node], end = offsets[node + 1];
    const char* tb = (const char*)t;
    const unsigned loff = li * 8u;
    float a0 = 0.f, a1 = 0.f, a2 = 0.f, a3 = 0.f;
    for (; p + 8 <= end; p += 8) {
        int2 ee[8];
        #pragma unroll
        for (int i = 0; i < 8; ++i) ee[i] = e_sw[p + i];
        uint2 vv[8];
        #pragma unroll
        for (int i = 0; i < 8; ++i)
            vv[i] = *reinterpret_cast<const uint2*>(tb + ((unsigned)ee[i].x * 128u + loff));
        #pragma unroll
        for (int i = 0; i < 8; ++i) {
            float w = i2f(ee[i].y);
            a0 += w * u2f(vv[i].x << 16); a1 += w * u2f(vv[i].x & 0xFFFF0000u);
            a2 += w * u2f(vv[i].y << 16); a3 += w * u2f(vv[i].y & 0xFFFF0000u);
        }
    }
    for (; p < end; ++p) {
        int2 e0 = e_sw[p];
        uint2 v0 = *reinterpret_cast<const uint2*>(tb + ((unsigned)e0.x * 128u + loff));
        float w = i2f(e0.y);
        a0 += w * u2f(v0.x << 16); a1 += w * u2f(v0.x & 0xFFFF0000u);
        a2 += w * u2f(v0.y << 16); a3 += w * u2f(v0.y & 0xFFFF0000u);
    }
    float4 r = *reinterpret_cast<const float4*>(root + (size_t)node * 64 + li * 4);
    float4 o = make_float4(r.x + a0, r.y + a1, r.z + a2, r.w + a3);
    *reinterpret_cast<float4*>(out + (size_t)node * 64 + li * 4) = o;
}

// ---------------- L0 GEMM: BM=128 x BN=256 (full width), 8 waves 2x4, wave tile 64x64 ----
// h = agg@Wr0.T + x@Wt0.T + br0 -> bf16 h_bf + fused col stats. A/X read ONCE.
template<int K, int O>
__global__ __launch_bounds__(512, 4) void gemm0_k(
        const unsigned short* __restrict__ A, const unsigned short* __restrict__ Wa,
        const unsigned short* __restrict__ X, const unsigned short* __restrict__ Wb,
        const float* __restrict__ bias, unsigned short* __restrict__ out_bf,
        float* __restrict__ sums, float* __restrict__ sumsq, int Nn) {
    constexpr int BM = 128;
    constexpr int MI = 4, OJ = 4;              // wave tile 64 x 64
    constexpr int KSTEPS = K / 32;
    constexpr int NT = 2 * KSTEPS;
    __shared__ unsigned short As[2][BM * 32];
    __shared__ unsigned short Bs[2][256 * 32];
    const int tid = threadIdx.x;
    const int w = tid >> 6, l = tid & 63;
    const int wr = w >> 2, wc = w & 3;
    const int lrow = l & 15, kgrp = l >> 4;
    int bx = blockIdx.x;
    bx = (bx & 7) * (gridDim.x >> 3) + (bx >> 3);
    const int m0 = bx * BM;
    const int srow = tid >> 2, sslot = tid & 3;
    const int gslot = sslot ^ ((srow >> 1) & 3);   // invariant under row+128 ((128>>1)&3 == 0)

    auto stage = [&](int buf, int t) {
        int ph = t / KSTEPS;
        int k0 = (t % KSTEPS) * 32;
        const unsigned short* Ap = ph ? X : A;
        const unsigned short* Wp = ph ? Wb : Wa;
        gload_lds16(Ap + (size_t)(m0 + srow) * K + k0 + (gslot << 3), &As[buf][w * 512]);
        #pragma unroll
        for (int i = 0; i < 2; ++i)
            gload_lds16(Wp + (size_t)(i * 128 + srow) * K + k0 + (gslot << 3),
                        &Bs[buf][i * 4096 + w * 512]);
    };

    f32x4 acc[MI][OJ];
    #pragma unroll
    for (int i = 0; i < MI; ++i)
        #pragma unroll
        for (int j = 0; j < OJ; ++j) {
            f32x4 z = {0.f, 0.f, 0.f, 0.f};
            acc[i][j] = z;
        }

    stage(0, 0);
    __syncthreads();
    #pragma unroll
    for (int t = 0; t < NT; ++t) {
        const int cur = t & 1;
        if (t + 1 < NT) stage(cur ^ 1, t + 1);
        bf16x8 a[MI], b[OJ];
        #pragma unroll
        for (int mi = 0; mi < MI; ++mi) {
            int row = wr * 64 + mi * 16 + lrow;
            int slot = kgrp ^ ((row >> 1) & 3);
            a[mi] = *reinterpret_cast<const bf16x8*>(&As[cur][row * 32 + slot * 8]);
        }
        #pragma unroll
        for (int oj = 0; oj < OJ; ++oj) {
            int row = wc * 64 + oj * 16 + lrow;
            int slot = kgrp ^ ((row >> 1) & 3);
            b[oj] = *reinterpret_cast<const bf16x8*>(&Bs[cur][row * 32 + slot * 8]);
        }
        #pragma unroll
        for (int mi = 0; mi < MI; ++mi)
            #pragma unroll
            for (int oj = 0; oj < OJ; ++oj)
                acc[mi][oj] = __builtin_amdgcn_mfma_f32_16x16x32_bf16(
                    a[mi], b[oj], acc[mi][oj], 0, 0, 0);
        __syncthreads();
    }

    #pragma unroll
    for (int oj = 0; oj < OJ; ++oj) {
        int col = wc * 64 + oj * 16 + lrow;
        float bcol = bias[col];
        float s = 0.f, q = 0.f;
        #pragma unroll
        for (int mi = 0; mi < MI; ++mi) {
            #pragma unroll
            for (int r = 0; r < 4; ++r) {
                int row = m0 + wr * 64 + mi * 16 + kgrp * 4 + r;
                float v = acc[mi][oj][r] + bcol;
                if (row < Nn) {
                    out_bf[(size_t)row * O + col] = f2bf(v);
                    s += v; q += v * v;
                }
            }
        }
        s += __shfl_xor(s, 16, 64); q += __shfl_xor(q, 16, 64);
        s += __shfl_xor(s, 32, 64); q += __shfl_xor(q, 32, 64);
        if (kgrp == 0) {
            atomicAdd(&sums[col], s);
            atomicAdd(&sumsq[col], q);
        }
    }
}

// ---------------- L1 GEMM, BN=256, fused BN+ReLU on the X operand ----------------
// h1 = agg@Wr1.T + relu(bn0(h_raw))@Wt1.T + br1. X reg-staged ONCE per block.
template<int K, int O>
__global__ __launch_bounds__(512, 4) void gemm1_bn_k(
        const unsigned short* __restrict__ A, const unsigned short* __restrict__ Wa,
        const unsigned short* __restrict__ X, const unsigned short* __restrict__ Wb,
        const float* __restrict__ sums0, const float* __restrict__ sumsq0,
        const float* __restrict__ g0, const float* __restrict__ be0,
        const float* __restrict__ bias, unsigned short* __restrict__ out_bf,
        float* __restrict__ sums1, float* __restrict__ sumsq1, float invN, int Nn) {
    constexpr int BM = 128;
    constexpr int MI = 4, OJ = 4;
    constexpr int KSTEPS = K / 32;                // 8
    constexpr int NT = 2 * KSTEPS;                // 16
    __shared__ unsigned short As[2][BM * 32];
    __shared__ unsigned short Bs[2][256 * 32];
    __shared__ float scs[256], shs[256];
    const int tid = threadIdx.x;
    const int w = tid >> 6, l = tid & 63;
    const int wr = w >> 2, wc = w & 3;
    const int lrow = l & 15, kgrp = l >> 4;
    int bx = blockIdx.x;
    bx = (bx & 7) * (gridDim.x >> 3) + (bx >> 3);
    const int m0 = bx * BM;
    const int srow = tid >> 2, sslot = tid & 3;
    const int gslot = sslot ^ ((srow >> 1) & 3);

    auto stageB = [&](int buf, int t) {
        int k0 = (t % KSTEPS) * 32;
        const unsigned short* Wp = (t < KSTEPS) ? Wa : Wb;
        #pragma unroll
        for (int i = 0; i < 2; ++i)
            gload_lds16(Wp + (size_t)(i * 128 + srow) * K + k0 + (gslot << 3),
                        &Bs[buf][i * 4096 + w * 512]);
    };
    auto stageA = [&](int buf, int t) {   // A-phase only
        int k0 = t * 32;
        gload_lds16(A + (size_t)(m0 + srow) * K + k0 + (gslot << 3), &As[buf][w * 512]);
    };
    auto loadX = [&](int t) -> bf16x8 {   // X-phase only
        int k0 = (t - KSTEPS) * 32;
        return *reinterpret_cast<const bf16x8*>(X + (size_t)(m0 + srow) * K + k0 + (gslot << 3));
    };
    auto writeX = [&](int buf, int t, bf16x8 raw) {
        int f0 = (t - KSTEPS) * 32 + (gslot << 3);
        bf16x8 o;
        #pragma unroll
        for (int j = 0; j < 8; ++j) {
            float v = bf2f((unsigned short)raw[j]) * scs[f0 + j] + shs[f0 + j];
            o[j] = (short)f2bf(fmaxf(v, 0.f));
        }
        *reinterpret_cast<bf16x8*>(&As[buf][tid * 8]) = o;
    };

    if (tid < 256) {
        float mu = sums0[tid] * invN;
        float var = sumsq0[tid] * invN - mu * mu;
        float sc = g0[tid] * rsqrtf(var + 1e-5f);
        scs[tid] = sc;
        shs[tid] = be0[tid] - mu * sc;
    }

    f32x4 acc[MI][OJ];
    #pragma unroll
    for (int i = 0; i < MI; ++i)
        #pragma unroll
        for (int j = 0; j < OJ; ++j) {
            f32x4 z = {0.f, 0.f, 0.f, 0.f};
            acc[i][j] = z;
        }

    stageB(0, 0);
    stageA(0, 0);
    __syncthreads();
    #pragma unroll
    for (int t = 0; t < NT; ++t) {
        const int cur = t & 1;
        bf16x8 nxt;
        const bool nxtReg = (t + 1 < NT) && (t + 1 >= KSTEPS);
        if (t + 1 < NT) {
            stageB(cur ^ 1, t + 1);
            if (t + 1 < KSTEPS) stageA(cur ^ 1, t + 1);
            else nxt = loadX(t + 1);
        }
        bf16x8 a[MI], b[OJ];
        #pragma unroll
        for (int mi = 0; mi < MI; ++mi) {
            int row = wr * 64 + mi * 16 + lrow;
            int slot = kgrp ^ ((row >> 1) & 3);
            a[mi] = *reinterpret_cast<const bf16x8*>(&As[cur][row * 32 + slot * 8]);
        }
        #pragma unroll
        for (int oj = 0; oj < OJ; ++oj) {
            int row = wc * 64 + oj * 16 + lrow;
            int slot = kgrp ^ ((row >> 1) & 3);
            b[oj] = *reinterpret_cast<const bf16x8*>(&Bs[cur][row * 32 + slot * 8]);
        }
        #pragma unroll
        for (int mi = 0; mi < MI; ++mi)
            #pragma unroll
            for (int oj = 0; oj < OJ; ++oj)
                acc[mi][oj] = __builtin_amdgcn_mfma_f32_16x16x32_bf16(
                    a[mi], b[oj], acc[mi][oj], 0, 0, 0);
        if (nxtReg) writeX(cur ^ 1, t + 1, nxt);
        __syncthreads();
    }

    #pragma unroll
    for (int oj = 0; oj < OJ; ++oj) {
        int col = wc * 64 + oj * 16 + lrow;
        float bcol = bias[col];
        float s = 0.f, q = 0.f;
        #pragma unroll
        for (int mi = 0; mi < MI; ++mi) {
            #pragma unroll
            for (int r = 0; r < 4; ++r) {
                int row = m0 + wr * 64 + mi * 16 + kgrp * 4 + r;
                float v = acc[mi][oj][r] + bcol;
                if (row < Nn) {
                    out_bf[(size_t)row * O + col] = f2bf(v);
                    s += v; q += v * v;
                }
            }
        }
        s += __shfl_xor(s, 16, 64); q += __shfl_xor(q, 16, 64);
        s += __shfl_xor(s, 32, 64); q += __shfl_xor(q, 32, 64);
        if (kgrp == 0) {
            atomicAdd(&sums1[col], s);
            atomicAdd(&sumsq1[col], q);
        }
    }
}

// ---------------- layer-2 GEMM: t|root = relu(bn1(h1N)) @ [Wr2|Wt2]^T (unchanged) ----
template<int K>
__global__ __launch_bounds__(512, 4) void gemm2_bn_k(
        const unsigned short* __restrict__ A, const unsigned short* __restrict__ Wa,
        const float* __restrict__ sums, const float* __restrict__ sumsq,
        const float* __restrict__ g, const float* __restrict__ be,
        const float* __restrict__ bias, unsigned short* __restrict__ t_bf,
        float* __restrict__ root, float invN, int Nn) {
    constexpr int BM = 128, BN = 128;
    constexpr int MI = 4, OJ = 2;
    constexpr int NT = K / 32;                 // 8
    __shared__ unsigned short As[2][BM * 32];
    __shared__ unsigned short Bs[2][BN * 32];
    __shared__ float scs[256], shs[256];
    const int tid = threadIdx.x;
    const int w = tid >> 6, l = tid & 63;
    const int wr = w >> 2, wc = w & 3;
    const int lrow = l & 15, kgrp = l >> 4;
    int bx = blockIdx.x;
    bx = (bx & 7) * (gridDim.x >> 3) + (bx >> 3);
    const int m0 = bx * BM;
    const int srow = tid >> 2, sslot = tid & 3;
    const int gslot = sslot ^ ((srow >> 1) & 3);

    auto stageW = [&](int buf, int t) {
        gload_lds16(Wa + (size_t)srow * K + t * 32 + (gslot << 3), &Bs[buf][w * 512]);
    };
    auto loadA = [&](int t) -> bf16x8 {
        return *reinterpret_cast<const bf16x8*>(A + (size_t)(m0 + srow) * K + t * 32 + (gslot << 3));
    };
    auto writeA = [&](int buf, int t, bf16x8 raw) {
        int f0 = t * 32 + (gslot << 3);
        bf16x8 o;
        #pragma unroll
        for (int j = 0; j < 8; ++j) {
            float v = bf2f((unsigned short)raw[j]) * scs[f0 + j] + shs[f0 + j];
            o[j] = (short)f2bf(fmaxf(v, 0.f));
        }
        *reinterpret_cast<bf16x8*>(&As[buf][tid * 8]) = o;
    };

    if (tid < 256) {
        float mu = sums[tid] * invN;
        float var = sumsq[tid] * invN - mu * mu;
        float sc = g[tid] * rsqrtf(var + 1e-5f);
        scs[tid] = sc;
        shs[tid] = be[tid] - mu * sc;
    }

    f32x4 acc[MI][OJ];
    #pragma unroll
    for (int i = 0; i < MI; ++i)
        #pragma unroll
        for (int j = 0; j < OJ; ++j) {
            f32x4 z = {0.f, 0.f, 0.f, 0.f};
            acc[i][j] = z;
        }

    bf16x8 r0 = loadA(0);
    stageW(0, 0);
    __syncthreads();            // scs/shs ready
    writeA(0, 0, r0);
    __syncthreads();            // As[0] ready
    #pragma unroll
    for (int t = 0; t < NT; ++t) {
        const int cur = t & 1;
        bf16x8 nxt;
        if (t + 1 < NT) { nxt = loadA(t + 1); stageW(cur ^ 1, t + 1); }
        bf16x8 a[MI], b[OJ];
        #pragma unroll
        for (int mi = 0; mi < MI; ++mi) {
            int row = wr * 64 + mi * 16 + lrow;
            int slot = kgrp ^ ((row >> 1) & 3);
            a[mi] = *reinterpret_cast<const bf16x8*>(&As[cur][row * 32 + slot * 8]);
        }
        #pragma unroll
        for (int oj = 0; oj < OJ; ++oj) {
            int row = wc * 32 + oj * 16 + lrow;
            int slot = kgrp ^ ((row >> 1) & 3);
            b[oj] = *reinterpret_cast<const bf16x8*>(&Bs[cur][row * 32 + slot * 8]);
        }
        #pragma unroll
        for (int mi = 0; mi < MI; ++mi)
            #pragma unroll
            for (int oj = 0; oj < OJ; ++oj)
                acc[mi][oj] = __builtin_amdgcn_mfma_f32_16x16x32_bf16(
                    a[mi], b[oj], acc[mi][oj], 0, 0, 0);
        if (t + 1 < NT) writeA(cur ^ 1, t + 1, nxt);
        __syncthreads();
    }

    #pragma unroll
    for (int oj = 0; oj < OJ; ++oj) {
        int col = wc * 32 + oj * 16 + lrow;
        #pragma unroll
        for (int mi = 0; mi < MI; ++mi) {
            #pragma unroll
            for (int r = 0; r < 4; ++r) {
                int row = m0 + wr * 64 + mi * 16 + kgrp * 4 + r;
                if (row < Nn) {
                    if (col < 64)
                        t_bf[(size_t)row * 64 + col] = f2bf(acc[mi][oj][r]);
                    else
                        root[(size_t)row * 64 + (col - 64)] = acc[mi][oj][r] + bias[col - 64];
                }
            }
        }
    }
}

extern "C" void kernel_launch(void* const* d_in, const int* in_sizes, int n_in,
                              void* d_out, int out_size, void* d_ws, size_t ws_size,
                              hipStream_t stream) {
    const float* x   = (const float*)d_in[0];
    const int*   ei  = (const int*)d_in[1];
    const float* ew  = (const float*)d_in[2];
    const float* Wr0 = (const float*)d_in[3];
    const float* br0 = (const float*)d_in[4];
    const float* Wt0 = (const float*)d_in[5];
    const float* g0  = (const float*)d_in[6];
    const float* be0 = (const float*)d_in[7];
    const float* Wr1 = (const float*)d_in[8];
    const float* br1 = (const float*)d_in[9];
    const float* Wt1 = (const float*)d_in[10];
    const float* g1  = (const float*)d_in[11];
    const float* be1 = (const float*)d_in[12];
    const float* Wr2 = (const float*)d_in[13];
    const float* br2 = (const float*)d_in[14];
    const float* Wt2 = (const float*)d_in[15];

    const int E  = in_sizes[2];          // 800000
    const int Nn = in_sizes[0] / 128;    // 50000
    const size_t NP = 50176;             // padded rows (NP/128 % 8 == 0)
    const int* src = ei;
    const int* dst = ei + E;

    // ---- workspace layout ----
    unsigned short* x_bf   = (unsigned short*)d_ws;        // NP*128
    unsigned short* agg_bf = x_bf + NP * 128;              // NP*256
    unsigned short* h1N    = agg_bf + NP * 256;            // NP*256 (L1 raw out)
    unsigned short* h_bf   = h1N + NP * 256;               // NP*256 (L0 raw out)
    unsigned short* t_bf   = h_bf + NP * 256;              // NP*64
    unsigned short* wbf    = t_bf + NP * 64;               // 229376
    unsigned short* Wr0b = wbf;
    unsigned short* Wt0b = wbf + 32768;
    unsigned short* Wr1b = wbf + 65536;
    unsigned short* Wt1b = wbf + 131072;
    unsigned short* W2cat = wbf + 196608;                  // Wr2 | Wt2
    float* root  = (float*)(wbf + 229376);                 // NP*64 f32
    int2*  e_sw  = (int2*)(root + NP * 64);                // E
    float* stats = (float*)(e_sw + E);                     // 4096 f
    int*   counts  = (int*)(stats + 4096);                 // Nn (memset with stats)
    int*   partial = counts + Nn;                          // Nn
    int*   blocksum = partial + Nn;                        // 512
    int*   rank    = blocksum + 512;                       // E
    int*   offsets = rank + E;                             // Nn+1

    dim3 blk(256);
    const int nbScan = (Nn + SCAN_B - 1) / SCAN_B;
    const float invN = 1.0f / (float)Nn;
    const int n4x = Nn * 32;
    const int histBlocks = (E + 255) / 256;
    const int convBlocks = (n4x + 57344 + 255) / 256;

    hipMemsetAsync(stats, 0, (4096 + (size_t)Nn) * sizeof(float), stream);

    // ---- CSR build fused with bf16 conversions ----
    hist_conv_k<<<dim3(histBlocks + convBlocks), blk, 0, stream>>>(
        dst, counts, rank, E, histBlocks,
        x, Wr0, Wt0, Wr1, Wt1, Wr2, Wt2,
        x_bf, Wr0b, Wt0b, Wr1b, Wt1b, W2cat, W2cat + 16384, n4x);
    scan1_k<<<dim3(nbScan), dim3(SCAN_B), 0, stream>>>(counts, partial, blocksum, Nn);
    scan3b_k<<<dim3(nbScan), dim3(SCAN_B), 0, stream>>>(partial, blocksum, offsets, Nn);
    fill2_k<<<dim3(histBlocks), blk, 0, stream>>>(src, dst, ew, offsets, rank, e_sw, E);

    const int gatherBlocks = (Nn * 64 + 255) / 256;   // 12500

    // ---------------- layer 0: K=128 -> 256 (full-width tile) ----------------
    gather128_k<<<dim3(gatherBlocks), blk, 0, stream>>>(x_bf, offsets, e_sw, agg_bf, Nn);
    gemm0_k<128, 256><<<dim3(NP / 128), dim3(512), 0, stream>>>(
        agg_bf, Wr0b, x_bf, Wt0b, br0, h_bf, stats + 0, stats + 256, Nn);

    // ---------------- layer 1: gather (inline BN0) then dual GEMM (X fused BN0) ----
    gather_bn_k<<<dim3(gatherBlocks), blk, 0, stream>>>(
        h_bf, stats + 0, stats + 256, g0, be0, offsets, e_sw, agg_bf, invN, Nn);
    gemm1_bn_k<256, 256><<<dim3(NP / 128), dim3(512), 0, stream>>>(
        agg_bf, Wr1b, h_bf, Wt1b, stats + 0, stats + 256, g0, be0,
        br1, h1N, stats + 1024, stats + 1280, invN, Nn);

    // ---------------- layer 2: transform-first with fused BN1 ----------------
    gemm2_bn_k<256><<<dim3(NP / 128), dim3(512), 0, stream>>>(
        h1N, W2cat, stats + 1024, stats + 1280, g1, be1, br2, t_bf, root, invN, Nn);
    gather_out_k<<<dim3((Nn * 16 + 255) / 256), blk, 0, stream>>>(
        t_bf, root, offsets, e_sw, (float*)d_out, Nn);
}